// Round 11
// baseline (311.076 us; speedup 1.0000x reference)
//
#include <hip/hip_runtime.h>
#include <hip/hip_bf16.h>
#include <stdint.h>
#include <string.h>

using u16 = unsigned short;
typedef __attribute__((ext_vector_type(8))) short short8;
typedef __attribute__((ext_vector_type(4))) float f32x4;

__device__ __forceinline__ u16 f2bf(float f) {
  union { float f; unsigned int u; } x; x.f = f;
  unsigned int u = x.u;
  return (u16)((u + 0x7fffu + ((u >> 16) & 1u)) >> 16);
}
__device__ __forceinline__ unsigned int pk_bf16(float a, float b) {
  float2 t; t.x = a; t.y = b;
  __hip_bfloat162 h = __float22bfloat162_rn(t);
  unsigned int u; memcpy(&u, &h, 4);
  return u;
}
__device__ __forceinline__ void gl_lds16(const u16* g, u16* l) {
  __builtin_amdgcn_global_load_lds((const __attribute__((address_space(1))) void*)g,
                                   (__attribute__((address_space(3))) void*)l, 16, 0, 0);
}

// P-redistribution: (W[t_even], W[t_odd]) -> (B[s][j], B[s][j+2]) in 2 permlane swaps.
__device__ __forceinline__ void pl_swap(unsigned int& a, unsigned int& b) {
  auto r1 = __builtin_amdgcn_permlane32_swap(a, b, false, false);
  auto r2 = __builtin_amdgcn_permlane16_swap(r1[0], r1[1], false, false);
  a = r2[0]; b = r2[1];
}

// scale(1/sqrt(64)) * log2(e), folded into Q at the QKV epilogue
#define SCALE_LOG2E 0.18033688011112042f

// ---------------- x ingestion: fp32 -> internal bf16 ----------------
__global__ void __launch_bounds__(256) conv_x(
    const float* __restrict__ in, u16* __restrict__ out, int n4) {
  const int t = blockIdx.x * 256 + threadIdx.x;
  if (t >= n4) return;
  const float4 v = ((const float4*)in)[t];
  uint2 o;
  o.x = pk_bf16(v.x, v.y);
  o.y = pk_bf16(v.z, v.w);
  ((uint2*)out)[t] = o;
}

// ---- 64x64-tile weight transpose, fp32 in -> bf16 out, all 4 weights via z ----
__global__ void __launch_bounds__(256) transpose_w(
    const float* __restrict__ W0, const float* __restrict__ W1,
    const float* __restrict__ W2, const float* __restrict__ W3,
    u16* __restrict__ Wt) {
  __shared__ alignas(16) u16 t[64][65];
  const int z = blockIdx.z;
  const float* in = (z == 0) ? W0 : (z == 1) ? W1 : (z == 2) ? W2 : W3;
  u16* out = Wt + (size_t)z * 1024 * 1024;
  const int tx = threadIdx.x & 63, ty = threadIdx.x >> 6;
  const int r0 = blockIdx.y * 64, c0 = blockIdx.x * 64;
#pragma unroll
  for (int rr = ty; rr < 64; rr += 4) t[rr][tx] = f2bf(in[(size_t)(r0 + rr) * 1024 + c0 + tx]);
  __syncthreads();
#pragma unroll
  for (int rr = ty; rr < 64; rr += 4) out[(size_t)(c0 + rr) * 1024 + r0 + tx] = t[tx][rr];
}

// ---------------- GEMM core: R8 version — 128x128 tile, BK=64, single-buffered,
// T2 swizzle (conflict-free: 8 slots x 8 lanes = 2 lanes/bank). Best-measured
// GEMM structure; dbuf/XCD/8-phase variants all regressed or were null (R6/R9).
// D-layout (verified): element (p, q) where p-dim comes from FIRST operand
// (rows p0 + wr*64 + i*16 + quad*4 + r) and q-dim from SECOND operand
// (rows q0 + wc*64 + j*16 + l16). Callers may swap operand order to choose
// which output dimension lands on the 4-consecutive register axis (r).
__device__ __forceinline__ void gemm_core(
    const u16* __restrict__ A, const u16* __restrict__ Bt,
    u16* As, u16* Bs, int m0, int n0, int K, f32x4 (&acc)[4][4]) {
  const int tid = threadIdx.x;
  const int wave = tid >> 6, lane = tid & 63;
  const int quad = lane >> 4, l16 = lane & 15;
  const int wr = wave >> 1, wc = wave & 1;
  const int lr8 = lane >> 3;                       // row within 8-row group
  const int cbg = ((lane & 7) ^ lr8) * 8;          // swizzled source chunk
  const int sw = (l16 & 7);                        // read-side swizzle
  for (int k0 = 0; k0 < K; k0 += 64) {
    __syncthreads();
#pragma unroll
    for (int u = 0; u < 4; ++u) {
      gl_lds16(A  + (size_t)(m0 + u * 32 + wave * 8 + lr8) * K + k0 + cbg,
               &As[u * 2048 + wave * 512]);
      gl_lds16(Bt + (size_t)(n0 + u * 32 + wave * 8 + lr8) * K + k0 + cbg,
               &Bs[u * 2048 + wave * 512]);
    }
    __syncthreads();
#pragma unroll
    for (int ks = 0; ks < 2; ++ks) {
      const int kc = ((ks * 4 + quad) ^ sw) * 8;
      short8 af[4], bfr[4];
#pragma unroll
      for (int i = 0; i < 4; ++i)
        af[i] = *(const short8*)&As[(wr * 64 + i * 16 + l16) * 64 + kc];
#pragma unroll
      for (int j = 0; j < 4; ++j)
        bfr[j] = *(const short8*)&Bs[(wc * 64 + j * 16 + l16) * 64 + kc];
#pragma unroll
      for (int i = 0; i < 4; ++i)
#pragma unroll
        for (int j = 0; j < 4; ++j)
          acc[i][j] = __builtin_amdgcn_mfma_f32_16x16x32_bf16(af[i], bfr[j], acc[i][j], 0, 0, 0);
    }
  }
}

// ---------------- fused QKV GEMM ----------------
// Q/K blocks run the core with OPERANDS SWAPPED (W first, x second): the output
// feature dim (n -> h,d) then owns the quad*4+r register axis -> 4 consecutive d
// per lane -> uint2 stores (16/thread) instead of 64 scalar u16 stores.
// Values are bit-identical (same dot products, same K accumulation order).
// V keeps the original orientation (s on the r-axis, already uint2-vectorized).
__global__ void __launch_bounds__(256) gemm_qkv(
    const u16* __restrict__ A, const u16* __restrict__ Wt,
    const float* __restrict__ bq, const float* __restrict__ bk, const float* __restrict__ bv,
    u16* __restrict__ Qb, u16* __restrict__ Kb, u16* __restrict__ Vtb) {
  __shared__ alignas(16) u16 As[128 * 64];
  __shared__ alignas(16) u16 Bs[128 * 64];
  const int tsel = blockIdx.x >> 3;
  const int n0 = (blockIdx.x & 7) * 128;
  const int m0 = blockIdx.y * 128;
  const u16* Bt = Wt + (size_t)tsel * 1048576;
  const float* bias = (tsel == 0) ? bq : (tsel == 1) ? bk : bv;

  f32x4 acc[4][4];
#pragma unroll
  for (int i = 0; i < 4; ++i)
#pragma unroll
    for (int j = 0; j < 4; ++j) acc[i][j] = (f32x4){0.f, 0.f, 0.f, 0.f};

  // wave-uniform operand order selection (single core instantiation)
  const u16* P0 = (tsel < 2) ? Bt : A;
  const u16* P1 = (tsel < 2) ? A : Bt;
  const int o0 = (tsel < 2) ? n0 : m0;
  const int o1 = (tsel < 2) ? m0 : n0;
  gemm_core(P0, P1, As, Bs, o0, o1, 1024, acc);

  const int tid = threadIdx.x;
  const int wave = tid >> 6, lane = tid & 63;
  const int quad = lane >> 4, l16 = lane & 15;
  const int wr = wave >> 1, wc = wave & 1;

  if (tsel < 2) {
    // swapped layout: acc[i][j] holds (n, m) with
    //   n = n0 + wr*64 + i*16 + quad*4 + r  (4 consecutive d per lane)
    //   m = m0 + wc*64 + j*16 + l16
    u16* C = tsel ? Kb : Qb;
    const float scl = tsel ? 1.0f : SCALE_LOG2E;
#pragma unroll
    for (int i = 0; i < 4; ++i) {
      const int nb = n0 + wr * 64 + i * 16 + quad * 4;
      const float4 bb = *(const float4*)&bias[nb];
      const int h = nb >> 6, d0 = nb & 63;
#pragma unroll
      for (int j = 0; j < 4; ++j) {
        const int m = m0 + wc * 64 + j * 16 + l16;
        const int b = m >> 11, s = m & 2047;
        uint2 o;
        o.x = pk_bf16((acc[i][j][0] + bb.x) * scl, (acc[i][j][1] + bb.y) * scl);
        o.y = pk_bf16((acc[i][j][2] + bb.z) * scl, (acc[i][j][3] + bb.w) * scl);
        *(uint2*)&C[((((size_t)b * 16 + h) * 2048) + s) * 64 + d0] = o;
      }
    }
  } else {
    // original layout: acc[i][j] holds (m, n) with m = ..+quad*4+r (4 consecutive s)
#pragma unroll
    for (int j = 0; j < 4; ++j) {
      const int n = n0 + wc * 64 + j * 16 + l16;
      const float bvf = bias[n];
      const int h = n >> 6, d = n & 63;
#pragma unroll
      for (int i = 0; i < 4; ++i) {
        const int mbase = m0 + wr * 64 + i * 16 + quad * 4;  // s, multiple of 4
        const int b = mbase >> 11, s = mbase & 2047;
        uint2 o;
        o.x = pk_bf16(acc[i][j][0] + bvf, acc[i][j][1] + bvf);
        o.y = pk_bf16(acc[i][j][2] + bvf, acc[i][j][3] + bvf);
        *(uint2*)&Vtb[(((size_t)b * 16 + h) * 64 + d) * 2048 + s] = o;
      }
    }
  }
}

// ---------------- output-projection GEMM: fp32 out, swapped orientation ----------
// Swapped operands put n on the quad*4+r axis -> float4 stores (16/thread)
// instead of 64 scalar fp32 stores at stride N.
__global__ void __launch_bounds__(256) gemm_out(
    const u16* __restrict__ A, const u16* __restrict__ Bt,
    const float* __restrict__ bias, float* __restrict__ C, int N) {
  __shared__ alignas(16) u16 As[128 * 64];
  __shared__ alignas(16) u16 Bs[128 * 64];
  const int m0 = blockIdx.y * 128;
  const int n0 = blockIdx.x * 128;
  f32x4 acc[4][4];
#pragma unroll
  for (int i = 0; i < 4; ++i)
#pragma unroll
    for (int j = 0; j < 4; ++j) acc[i][j] = (f32x4){0.f, 0.f, 0.f, 0.f};

  gemm_core(Bt, A, As, Bs, n0, m0, 1024, acc);   // swapped

  const int tid = threadIdx.x;
  const int wave = tid >> 6, lane = tid & 63;
  const int quad = lane >> 4, l16 = lane & 15;
  const int wr = wave >> 1, wc = wave & 1;
#pragma unroll
  for (int i = 0; i < 4; ++i) {
    const int nb = n0 + wr * 64 + i * 16 + quad * 4;
    const float4 bb = *(const float4*)&bias[nb];
#pragma unroll
    for (int j = 0; j < 4; ++j) {
      const int m = m0 + wc * 64 + j * 16 + l16;
      float4 o;
      o.x = acc[i][j][0] + bb.x;
      o.y = acc[i][j][1] + bb.y;
      o.z = acc[i][j][2] + bb.z;
      o.w = acc[i][j][3] + bb.w;
      *(float4*)&C[(size_t)m * N + nb] = o;
    }
  }
}

// ---------------- Flash attention: R10 version (K/V dbuf, Q->reg, 32 KB LDS) ----
__global__ void __launch_bounds__(256) flash_attn(
    const u16* __restrict__ Q, const u16* __restrict__ Kp,
    const u16* __restrict__ Vt, u16* __restrict__ Aout) {
  __shared__ alignas(16) u16 Ks[2][64 * 64];
  __shared__ alignas(16) u16 Vs[2][64 * 64];       // [d][s] tiles

  const int tid = threadIdx.x;
  const int wave = tid >> 6;
  const int lane = tid & 63;
  const int quad = lane >> 4;
  const int l16 = lane & 15;

  // bijective XCD-clustering remap of the 1024-block grid
  const int i = blockIdx.x;
  const int bh = (i & 7) * 8 + (i >> 7);           // XCD (i&7) owns 8 consecutive heads
  const int q0 = ((i >> 3) & 15) * 128;
  const int b = bh >> 4, h = bh & 15;

  const u16* Qg = Q + (size_t)bh * 2048 * 64;
  const u16* Kg = Kp + (size_t)bh * 2048 * 64;
  const u16* Vg = Vt + (size_t)bh * 64 * 2048;

  const int lr8 = lane >> 3;                       // row within 8-row chunk
  const int cbg = ((lane & 7) ^ lr8) * 8;          // swizzled global chunk offset

  // prologue: stage K/V tile 0 into buf 0
#pragma unroll
  for (int t = 0; t < 2; ++t) {
    const int c = wave * 2 + t;
    gl_lds16(Kg + (size_t)(c * 8 + lr8) * 64 + cbg, &Ks[0][c * 8 * 64]);
    gl_lds16(Vg + (size_t)(c * 8 + lr8) * 2048 + cbg, &Vs[0][c * 8 * 64]);
  }

  // Q fragments: direct global->reg, one time (loop-invariant, bit-identical)
  short8 qf[2][2];
#pragma unroll
  for (int qb = 0; qb < 2; ++qb)
#pragma unroll
    for (int ks = 0; ks < 2; ++ks)
      qf[qb][ks] = *(const short8*)&Qg[(size_t)(q0 + wave * 32 + qb * 16 + l16) * 64 + (ks * 4 + quad) * 8];

  f32x4 oacc[2][4];
#pragma unroll
  for (int qb = 0; qb < 2; ++qb)
#pragma unroll
    for (int t = 0; t < 4; ++t) oacc[qb][t] = (f32x4){0.f, 0.f, 0.f, 0.f};
  f32x4 lacc[2];
  lacc[0] = (f32x4){0.f, 0.f, 0.f, 0.f};
  lacc[1] = (f32x4){0.f, 0.f, 0.f, 0.f};
  const int sw = (l16 & 7) * 8;                    // fragment-read swizzle

  short8 ones;
#pragma unroll
  for (int i2 = 0; i2 < 8; ++i2) ones[i2] = (short)0x3F80;  // 1.0 bf16

  // barrier drains tile-0 K/V staging
  __syncthreads();

  for (int kt = 0; kt < 32; ++kt) {
    const int p = kt & 1;
    if (kt + 1 < 32) {
      const int s1 = (kt + 1) * 64;
#pragma unroll
      for (int t = 0; t < 2; ++t) {
        const int c = wave * 2 + t;
        gl_lds16(Kg + (size_t)(s1 + c * 8 + lr8) * 64 + cbg, &Ks[p ^ 1][c * 8 * 64]);
        gl_lds16(Vg + (size_t)(c * 8 + lr8) * 2048 + s1 + cbg, &Vs[p ^ 1][c * 8 * 64]);
      }
    }
    const u16* Kc = &Ks[p][0];
    const u16* Vc = &Vs[p][0];

    // S^T = K-tile @ Q^T  (Q pre-scaled by scale*log2e)
    f32x4 sacc[2][4];
#pragma unroll
    for (int qb = 0; qb < 2; ++qb)
#pragma unroll
      for (int t = 0; t < 4; ++t) sacc[qb][t] = (f32x4){0.f, 0.f, 0.f, 0.f};
#pragma unroll
    for (int ks = 0; ks < 2; ++ks) {
#pragma unroll
      for (int t = 0; t < 4; ++t) {
        const short8 akf = *(const short8*)&Kc[(t * 16 + l16) * 64 + (((ks * 4 + quad) * 8) ^ sw)];
#pragma unroll
        for (int qb = 0; qb < 2; ++qb)
          sacc[qb][t] = __builtin_amdgcn_mfma_f32_16x16x32_bf16(akf, qf[qb][ks], sacc[qb][t], 0, 0, 0);
      }
    }

    // max-free softmax + in-register redistribution to B-fragment layout.
    short8 bpf[2][2];
#pragma unroll
    for (int qb = 0; qb < 2; ++qb) {
      unsigned int w[4][2];
#pragma unroll
      for (int t = 0; t < 4; ++t) {
        const float p0 = __builtin_amdgcn_exp2f(sacc[qb][t][0]);
        const float p1 = __builtin_amdgcn_exp2f(sacc[qb][t][1]);
        const float p2 = __builtin_amdgcn_exp2f(sacc[qb][t][2]);
        const float p3 = __builtin_amdgcn_exp2f(sacc[qb][t][3]);
        w[t][0] = pk_bf16(p0, p1);
        w[t][1] = pk_bf16(p2, p3);
      }
      pl_swap(w[0][0], w[1][0]);
      pl_swap(w[0][1], w[1][1]);
      pl_swap(w[2][0], w[3][0]);
      pl_swap(w[2][1], w[3][1]);
      union { short8 s8; unsigned int u[4]; } pb;
      pb.u[0] = w[0][0]; pb.u[1] = w[0][1]; pb.u[2] = w[1][0]; pb.u[3] = w[1][1];
      bpf[qb][0] = pb.s8;
      pb.u[0] = w[2][0]; pb.u[1] = w[2][1]; pb.u[2] = w[3][0]; pb.u[3] = w[3][1];
      bpf[qb][1] = pb.s8;
    }

    // l += ones @ P^T (row-sum on the matrix pipe)
#pragma unroll
    for (int s = 0; s < 2; ++s)
#pragma unroll
      for (int qb = 0; qb < 2; ++qb)
        lacc[qb] = __builtin_amdgcn_mfma_f32_16x16x32_bf16(ones, bpf[qb][s], lacc[qb], 0, 0, 0);

    // O^T += V-tile @ P^T
#pragma unroll
    for (int s = 0; s < 2; ++s) {
#pragma unroll
      for (int t = 0; t < 4; ++t) {
        const short8 avf = *(const short8*)&Vc[(t * 16 + l16) * 64 + (((s * 4 + quad) * 8) ^ sw)];
#pragma unroll
        for (int qb = 0; qb < 2; ++qb)
          oacc[qb][t] = __builtin_amdgcn_mfma_f32_16x16x32_bf16(avf, bpf[qb][s], oacc[qb][t], 0, 0, 0);
      }
    }

    // single barrier per iter: drains next-tile staging (vmcnt) and orders
    // this iter's LDS reads before the next overwrite of buf^1
    __syncthreads();
  }

#pragma unroll
  for (int qb = 0; qb < 2; ++qb) {
    const float inv = 1.0f / lacc[qb][0];
    const int qrow = q0 + wave * 32 + qb * 16 + l16;
    const size_t base = ((size_t)b * 2048 + qrow) * 1024 + h * 64 + quad * 4;
#pragma unroll
    for (int t = 0; t < 4; ++t) {
      uint2 o;
      o.x = pk_bf16(oacc[qb][t][0] * inv, oacc[qb][t][1] * inv);
      o.y = pk_bf16(oacc[qb][t][2] * inv, oacc[qb][t][3] * inv);
      *(uint2*)&Aout[base + t * 16] = o;
    }
  }
}

extern "C" void kernel_launch(void* const* d_in, const int* in_sizes, int n_in,
                              void* d_out, int out_size, void* d_ws, size_t ws_size,
                              hipStream_t stream) {
  (void)in_sizes; (void)n_in; (void)out_size; (void)ws_size;
  const float* x  = (const float*)d_in[0];
  const float* Wq = (const float*)d_in[1];
  const float* bq = (const float*)d_in[2];
  const float* Wk = (const float*)d_in[3];
  const float* bk = (const float*)d_in[4];
  const float* Wv = (const float*)d_in[5];
  const float* bv = (const float*)d_in[6];
  const float* Wo = (const float*)d_in[7];
  const float* bo = (const float*)d_in[8];
  float* out = (float*)d_out;

  u16* ws = (u16*)d_ws;
  const size_t SZ = (size_t)4 * 16 * 2048 * 64;  // 16 MiB regions
  u16* xb   = ws;               // A (reused for Attn after gemm_qkv)
  u16* Qb   = ws + SZ;          // B
  u16* Kb   = ws + 2 * SZ;      // C
  u16* Vtb  = ws + 3 * SZ;      // D (V written directly transposed)
  u16* Wt   = ws + 4 * SZ;      // E (4 transposed weights)
  u16* Attn = ws;               // A alias

  conv_x<<<dim3(8192), dim3(256), 0, stream>>>(x, xb, 2097152);
  transpose_w<<<dim3(16, 16, 4), dim3(256), 0, stream>>>(Wq, Wk, Wv, Wo, Wt);
  gemm_qkv<<<dim3(24, 64), dim3(256), 0, stream>>>(xb, Wt, bq, bk, bv, Qb, Kb, Vtb);
  flash_attn<<<dim3(1024), dim3(256), 0, stream>>>(Qb, Kb, Vtb, Attn);
  gemm_out<<<dim3(8, 64), dim3(256), 0, stream>>>(Attn, Wt + (size_t)3 * 1048576, bo, out, 1024);
}

// Round 12
// 304.843 us; speedup vs baseline: 1.0204x; 1.0204x over previous
//
#include <hip/hip_runtime.h>
#include <hip/hip_bf16.h>
#include <stdint.h>
#include <string.h>

using u16 = unsigned short;
typedef __attribute__((ext_vector_type(8))) short short8;
typedef __attribute__((ext_vector_type(4))) float f32x4;

__device__ __forceinline__ u16 f2bf(float f) {
  union { float f; unsigned int u; } x; x.f = f;
  unsigned int u = x.u;
  return (u16)((u + 0x7fffu + ((u >> 16) & 1u)) >> 16);
}
__device__ __forceinline__ unsigned int pk_bf16(float a, float b) {
  float2 t; t.x = a; t.y = b;
  __hip_bfloat162 h = __float22bfloat162_rn(t);
  unsigned int u; memcpy(&u, &h, 4);
  return u;
}
__device__ __forceinline__ void gl_lds16(const u16* g, u16* l) {
  __builtin_amdgcn_global_load_lds((const __attribute__((address_space(1))) void*)g,
                                   (__attribute__((address_space(3))) void*)l, 16, 0, 0);
}

// P-redistribution: (W[t_even], W[t_odd]) -> (B[s][j], B[s][j+2]) in 2 permlane swaps.
__device__ __forceinline__ void pl_swap(unsigned int& a, unsigned int& b) {
  auto r1 = __builtin_amdgcn_permlane32_swap(a, b, false, false);
  auto r2 = __builtin_amdgcn_permlane16_swap(r1[0], r1[1], false, false);
  a = r2[0]; b = r2[1];
}

// scale(1/sqrt(64)) * log2(e), folded into Q at the QKV epilogue
#define SCALE_LOG2E 0.18033688011112042f

// ---------------- x ingestion: fp32 -> internal bf16 ----------------
__global__ void __launch_bounds__(256) conv_x(
    const float* __restrict__ in, u16* __restrict__ out, int n4) {
  const int t = blockIdx.x * 256 + threadIdx.x;
  if (t >= n4) return;
  const float4 v = ((const float4*)in)[t];
  uint2 o;
  o.x = pk_bf16(v.x, v.y);
  o.y = pk_bf16(v.z, v.w);
  ((uint2*)out)[t] = o;
}

// ---- 64x64-tile weight transpose, fp32 in -> bf16 out, all 4 weights via z ----
__global__ void __launch_bounds__(256) transpose_w(
    const float* __restrict__ W0, const float* __restrict__ W1,
    const float* __restrict__ W2, const float* __restrict__ W3,
    u16* __restrict__ Wt) {
  __shared__ alignas(16) u16 t[64][65];
  const int z = blockIdx.z;
  const float* in = (z == 0) ? W0 : (z == 1) ? W1 : (z == 2) ? W2 : W3;
  u16* out = Wt + (size_t)z * 1024 * 1024;
  const int tx = threadIdx.x & 63, ty = threadIdx.x >> 6;
  const int r0 = blockIdx.y * 64, c0 = blockIdx.x * 64;
#pragma unroll
  for (int rr = ty; rr < 64; rr += 4) t[rr][tx] = f2bf(in[(size_t)(r0 + rr) * 1024 + c0 + tx]);
  __syncthreads();
#pragma unroll
  for (int rr = ty; rr < 64; rr += 4) out[(size_t)(c0 + rr) * 1024 + r0 + tx] = t[tx][rr];
}

// ---------------- GEMM core: 128x128 tile, BK=64, single-buffered, T2 swizzle ----
// Best-measured GEMM structure (R8/R10, total 304.0). Conflict-free LDS reads
// (8 slots x 8 lanes = 2 lanes/bank). Epilogues keep the l16-on-contiguous-dim
// orientation: coalescing across lanes beats per-lane vector width (R11 lesson).
// dbuf/XCD/8-phase/operand-swap variants all regressed or were null (R6/R9/R11).
__device__ __forceinline__ void gemm_core(
    const u16* __restrict__ A, const u16* __restrict__ Bt,
    u16* As, u16* Bs, int m0, int n0, int K, f32x4 (&acc)[4][4]) {
  const int tid = threadIdx.x;
  const int wave = tid >> 6, lane = tid & 63;
  const int quad = lane >> 4, l16 = lane & 15;
  const int wr = wave >> 1, wc = wave & 1;
  const int lr8 = lane >> 3;                       // row within 8-row group
  const int cbg = ((lane & 7) ^ lr8) * 8;          // swizzled source chunk
  const int sw = (l16 & 7);                        // read-side swizzle
  for (int k0 = 0; k0 < K; k0 += 64) {
    __syncthreads();
#pragma unroll
    for (int u = 0; u < 4; ++u) {
      gl_lds16(A  + (size_t)(m0 + u * 32 + wave * 8 + lr8) * K + k0 + cbg,
               &As[u * 2048 + wave * 512]);
      gl_lds16(Bt + (size_t)(n0 + u * 32 + wave * 8 + lr8) * K + k0 + cbg,
               &Bs[u * 2048 + wave * 512]);
    }
    __syncthreads();
#pragma unroll
    for (int ks = 0; ks < 2; ++ks) {
      const int kc = ((ks * 4 + quad) ^ sw) * 8;
      short8 af[4], bfr[4];
#pragma unroll
      for (int i = 0; i < 4; ++i)
        af[i] = *(const short8*)&As[(wr * 64 + i * 16 + l16) * 64 + kc];
#pragma unroll
      for (int j = 0; j < 4; ++j)
        bfr[j] = *(const short8*)&Bs[(wc * 64 + j * 16 + l16) * 64 + kc];
#pragma unroll
      for (int i = 0; i < 4; ++i)
#pragma unroll
        for (int j = 0; j < 4; ++j)
          acc[i][j] = __builtin_amdgcn_mfma_f32_16x16x32_bf16(af[i], bfr[j], acc[i][j], 0, 0, 0);
    }
  }
}

// ---------------- fused QKV GEMM ----------------
__global__ void __launch_bounds__(256) gemm_qkv(
    const u16* __restrict__ A, const u16* __restrict__ Wt,
    const float* __restrict__ bq, const float* __restrict__ bk, const float* __restrict__ bv,
    u16* __restrict__ Qb, u16* __restrict__ Kb, u16* __restrict__ Vtb) {
  __shared__ alignas(16) u16 As[128 * 64];
  __shared__ alignas(16) u16 Bs[128 * 64];
  const int tsel = blockIdx.x >> 3;
  const int n0 = (blockIdx.x & 7) * 128;
  const int m0 = blockIdx.y * 128;
  const u16* Bt = Wt + (size_t)tsel * 1048576;
  const float* bias = (tsel == 0) ? bq : (tsel == 1) ? bk : bv;

  f32x4 acc[4][4];
#pragma unroll
  for (int i = 0; i < 4; ++i)
#pragma unroll
    for (int j = 0; j < 4; ++j) acc[i][j] = (f32x4){0.f, 0.f, 0.f, 0.f};

  gemm_core(A, Bt, As, Bs, m0, n0, 1024, acc);

  const int tid = threadIdx.x;
  const int wave = tid >> 6, lane = tid & 63;
  const int quad = lane >> 4, l16 = lane & 15;
  const int wr = wave >> 1, wc = wave & 1;

  if (tsel < 2) {
    u16* C = tsel ? Kb : Qb;
    const float scl = tsel ? 1.0f : SCALE_LOG2E;  // fold softmax scale*log2e into Q
#pragma unroll
    for (int j = 0; j < 4; ++j) {
      const int n = n0 + wc * 64 + j * 16 + l16;
      const float bvf = bias[n];
      const int h = n >> 6, d = n & 63;
#pragma unroll
      for (int i = 0; i < 4; ++i) {
        const int mbase = m0 + wr * 64 + i * 16 + quad * 4;
#pragma unroll
        for (int r = 0; r < 4; ++r) {
          const int m = mbase + r;
          const int b = m >> 11, s = m & 2047;
          C[((((size_t)b * 16 + h) * 2048) + s) * 64 + d] = f2bf((acc[i][j][r] + bvf) * scl);
        }
      }
    }
  } else {
#pragma unroll
    for (int j = 0; j < 4; ++j) {
      const int n = n0 + wc * 64 + j * 16 + l16;
      const float bvf = bias[n];
      const int h = n >> 6, d = n & 63;
#pragma unroll
      for (int i = 0; i < 4; ++i) {
        const int mbase = m0 + wr * 64 + i * 16 + quad * 4;  // s, multiple of 4
        const int b = mbase >> 11, s = mbase & 2047;
        uint2 o;
        o.x = pk_bf16(acc[i][j][0] + bvf, acc[i][j][1] + bvf);
        o.y = pk_bf16(acc[i][j][2] + bvf, acc[i][j][3] + bvf);
        *(uint2*)&Vtb[(((size_t)b * 16 + h) * 64 + d) * 2048 + s] = o;
      }
    }
  }
}

// ---------------- output-projection GEMM: fp32 out ----------------
__global__ void __launch_bounds__(256) gemm_out(
    const u16* __restrict__ A, const u16* __restrict__ Bt,
    const float* __restrict__ bias, float* __restrict__ C, int N) {
  __shared__ alignas(16) u16 As[128 * 64];
  __shared__ alignas(16) u16 Bs[128 * 64];
  const int m0 = blockIdx.y * 128;
  const int n0 = blockIdx.x * 128;
  f32x4 acc[4][4];
#pragma unroll
  for (int i = 0; i < 4; ++i)
#pragma unroll
    for (int j = 0; j < 4; ++j) acc[i][j] = (f32x4){0.f, 0.f, 0.f, 0.f};

  gemm_core(A, Bt, As, Bs, m0, n0, 1024, acc);

  const int tid = threadIdx.x;
  const int wave = tid >> 6, lane = tid & 63;
  const int quad = lane >> 4, l16 = lane & 15;
  const int wr = wave >> 1, wc = wave & 1;
#pragma unroll
  for (int j = 0; j < 4; ++j) {
    const int n = n0 + wc * 64 + j * 16 + l16;
    const float bvf = bias[n];
#pragma unroll
    for (int i = 0; i < 4; ++i) {
      const int mbase = m0 + wr * 64 + i * 16 + quad * 4;
#pragma unroll
      for (int r = 0; r < 4; ++r)
        C[(size_t)(mbase + r) * N + n] = acc[i][j][r] + bvf;
    }
  }
}

// ---------------- Flash attention: K/V LDS dbuf, Q direct-to-reg (32 KB LDS) ----
// Q,K: [bh][s][64], Vt: [bh][d][s]. Out: [b][s][h*64+d] bf16.
// Session-final structure: XCD-clustered grid (FETCH ~= ideal), K/V double-buffer
// with single barrier/iter, Q fragments straight to registers, max-free softmax
// (Q pre-scaled by scale*log2e), in-register P redistribution via permlane swaps,
// row-sum on the MFMA pipe. Pinned at ~122 us by its per-iter serial chain
// (5 orthogonal interventions null: R2 LDS-halving, R4 dbuf, R5 XCD, R7 LDS-free,
// R10 occupancy unbind).
__global__ void __launch_bounds__(256) flash_attn(
    const u16* __restrict__ Q, const u16* __restrict__ Kp,
    const u16* __restrict__ Vt, u16* __restrict__ Aout) {
  __shared__ alignas(16) u16 Ks[2][64 * 64];
  __shared__ alignas(16) u16 Vs[2][64 * 64];       // [d][s] tiles

  const int tid = threadIdx.x;
  const int wave = tid >> 6;
  const int lane = tid & 63;
  const int quad = lane >> 4;
  const int l16 = lane & 15;

  // bijective XCD-clustering remap of the 1024-block grid
  const int i = blockIdx.x;
  const int bh = (i & 7) * 8 + (i >> 7);           // XCD (i&7) owns 8 consecutive heads
  const int q0 = ((i >> 3) & 15) * 128;
  const int b = bh >> 4, h = bh & 15;

  const u16* Qg = Q + (size_t)bh * 2048 * 64;
  const u16* Kg = Kp + (size_t)bh * 2048 * 64;
  const u16* Vg = Vt + (size_t)bh * 64 * 2048;

  const int lr8 = lane >> 3;                       // row within 8-row chunk
  const int cbg = ((lane & 7) ^ lr8) * 8;          // swizzled global chunk offset

  // prologue: stage K/V tile 0 into buf 0
#pragma unroll
  for (int t = 0; t < 2; ++t) {
    const int c = wave * 2 + t;
    gl_lds16(Kg + (size_t)(c * 8 + lr8) * 64 + cbg, &Ks[0][c * 8 * 64]);
    gl_lds16(Vg + (size_t)(c * 8 + lr8) * 2048 + cbg, &Vs[0][c * 8 * 64]);
  }

  // Q fragments: direct global->reg, one time (loop-invariant, bit-identical)
  short8 qf[2][2];
#pragma unroll
  for (int qb = 0; qb < 2; ++qb)
#pragma unroll
    for (int ks = 0; ks < 2; ++ks)
      qf[qb][ks] = *(const short8*)&Qg[(size_t)(q0 + wave * 32 + qb * 16 + l16) * 64 + (ks * 4 + quad) * 8];

  f32x4 oacc[2][4];
#pragma unroll
  for (int qb = 0; qb < 2; ++qb)
#pragma unroll
    for (int t = 0; t < 4; ++t) oacc[qb][t] = (f32x4){0.f, 0.f, 0.f, 0.f};
  f32x4 lacc[2];
  lacc[0] = (f32x4){0.f, 0.f, 0.f, 0.f};
  lacc[1] = (f32x4){0.f, 0.f, 0.f, 0.f};
  const int sw = (l16 & 7) * 8;                    // fragment-read swizzle

  short8 ones;
#pragma unroll
  for (int i2 = 0; i2 < 8; ++i2) ones[i2] = (short)0x3F80;  // 1.0 bf16

  // barrier drains tile-0 K/V staging
  __syncthreads();

  for (int kt = 0; kt < 32; ++kt) {
    const int p = kt & 1;
    if (kt + 1 < 32) {
      const int s1 = (kt + 1) * 64;
#pragma unroll
      for (int t = 0; t < 2; ++t) {
        const int c = wave * 2 + t;
        gl_lds16(Kg + (size_t)(s1 + c * 8 + lr8) * 64 + cbg, &Ks[p ^ 1][c * 8 * 64]);
        gl_lds16(Vg + (size_t)(c * 8 + lr8) * 2048 + s1 + cbg, &Vs[p ^ 1][c * 8 * 64]);
      }
    }
    const u16* Kc = &Ks[p][0];
    const u16* Vc = &Vs[p][0];

    // S^T = K-tile @ Q^T  (Q pre-scaled by scale*log2e)
    f32x4 sacc[2][4];
#pragma unroll
    for (int qb = 0; qb < 2; ++qb)
#pragma unroll
      for (int t = 0; t < 4; ++t) sacc[qb][t] = (f32x4){0.f, 0.f, 0.f, 0.f};
#pragma unroll
    for (int ks = 0; ks < 2; ++ks) {
#pragma unroll
      for (int t = 0; t < 4; ++t) {
        const short8 akf = *(const short8*)&Kc[(t * 16 + l16) * 64 + (((ks * 4 + quad) * 8) ^ sw)];
#pragma unroll
        for (int qb = 0; qb < 2; ++qb)
          sacc[qb][t] = __builtin_amdgcn_mfma_f32_16x16x32_bf16(akf, qf[qb][ks], sacc[qb][t], 0, 0, 0);
      }
    }

    // max-free softmax + in-register redistribution to B-fragment layout.
    short8 bpf[2][2];
#pragma unroll
    for (int qb = 0; qb < 2; ++qb) {
      unsigned int w[4][2];
#pragma unroll
      for (int t = 0; t < 4; ++t) {
        const float p0 = __builtin_amdgcn_exp2f(sacc[qb][t][0]);
        const float p1 = __builtin_amdgcn_exp2f(sacc[qb][t][1]);
        const float p2 = __builtin_amdgcn_exp2f(sacc[qb][t][2]);
        const float p3 = __builtin_amdgcn_exp2f(sacc[qb][t][3]);
        w[t][0] = pk_bf16(p0, p1);
        w[t][1] = pk_bf16(p2, p3);
      }
      pl_swap(w[0][0], w[1][0]);
      pl_swap(w[0][1], w[1][1]);
      pl_swap(w[2][0], w[3][0]);
      pl_swap(w[2][1], w[3][1]);
      union { short8 s8; unsigned int u[4]; } pb;
      pb.u[0] = w[0][0]; pb.u[1] = w[0][1]; pb.u[2] = w[1][0]; pb.u[3] = w[1][1];
      bpf[qb][0] = pb.s8;
      pb.u[0] = w[2][0]; pb.u[1] = w[2][1]; pb.u[2] = w[3][0]; pb.u[3] = w[3][1];
      bpf[qb][1] = pb.s8;
    }

    // l += ones @ P^T (row-sum on the matrix pipe)
#pragma unroll
    for (int s = 0; s < 2; ++s)
#pragma unroll
      for (int qb = 0; qb < 2; ++qb)
        lacc[qb] = __builtin_amdgcn_mfma_f32_16x16x32_bf16(ones, bpf[qb][s], lacc[qb], 0, 0, 0);

    // O^T += V-tile @ P^T
#pragma unroll
    for (int s = 0; s < 2; ++s) {
#pragma unroll
      for (int t = 0; t < 4; ++t) {
        const short8 avf = *(const short8*)&Vc[(t * 16 + l16) * 64 + (((s * 4 + quad) * 8) ^ sw)];
#pragma unroll
        for (int qb = 0; qb < 2; ++qb)
          oacc[qb][t] = __builtin_amdgcn_mfma_f32_16x16x32_bf16(avf, bpf[qb][s], oacc[qb][t], 0, 0, 0);
      }
    }

    // single barrier per iter: drains next-tile staging (vmcnt) and orders
    // this iter's LDS reads before the next overwrite of buf^1
    __syncthreads();
  }

#pragma unroll
  for (int qb = 0; qb < 2; ++qb) {
    const float inv = 1.0f / lacc[qb][0];
    const int qrow = q0 + wave * 32 + qb * 16 + l16;
    const size_t base = ((size_t)b * 2048 + qrow) * 1024 + h * 64 + quad * 4;
#pragma unroll
    for (int t = 0; t < 4; ++t) {
      uint2 o;
      o.x = pk_bf16(oacc[qb][t][0] * inv, oacc[qb][t][1] * inv);
      o.y = pk_bf16(oacc[qb][t][2] * inv, oacc[qb][t][3] * inv);
      *(uint2*)&Aout[base + t * 16] = o;
    }
  }
}

extern "C" void kernel_launch(void* const* d_in, const int* in_sizes, int n_in,
                              void* d_out, int out_size, void* d_ws, size_t ws_size,
                              hipStream_t stream) {
  (void)in_sizes; (void)n_in; (void)out_size; (void)ws_size;
  const float* x  = (const float*)d_in[0];
  const float* Wq = (const float*)d_in[1];
  const float* bq = (const float*)d_in[2];
  const float* Wk = (const float*)d_in[3];
  const float* bk = (const float*)d_in[4];
  const float* Wv = (const float*)d_in[5];
  const float* bv = (const float*)d_in[6];
  const float* Wo = (const float*)d_in[7];
  const float* bo = (const float*)d_in[8];
  float* out = (float*)d_out;

  u16* ws = (u16*)d_ws;
  const size_t SZ = (size_t)4 * 16 * 2048 * 64;  // 16 MiB regions
  u16* xb   = ws;               // A (reused for Attn after gemm_qkv)
  u16* Qb   = ws + SZ;          // B
  u16* Kb   = ws + 2 * SZ;      // C
  u16* Vtb  = ws + 3 * SZ;      // D (V written directly transposed)
  u16* Wt   = ws + 4 * SZ;      // E (4 transposed weights)
  u16* Attn = ws;               // A alias

  conv_x<<<dim3(8192), dim3(256), 0, stream>>>(x, xb, 2097152);
  transpose_w<<<dim3(16, 16, 4), dim3(256), 0, stream>>>(Wq, Wk, Wv, Wo, Wt);
  gemm_qkv<<<dim3(24, 64), dim3(256), 0, stream>>>(xb, Wt, bq, bk, bv, Qb, Kb, Vtb);
  flash_attn<<<dim3(1024), dim3(256), 0, stream>>>(Qb, Kb, Vtb, Attn);
  gemm_out<<<dim3(8, 64), dim3(256), 0, stream>>>(Attn, Wt + (size_t)3 * 1048576, bo, out, 1024);
}

// Round 13
// 297.957 us; speedup vs baseline: 1.0440x; 1.0231x over previous
//
#include <hip/hip_runtime.h>
#include <hip/hip_bf16.h>
#include <stdint.h>
#include <string.h>

using u16 = unsigned short;
typedef __attribute__((ext_vector_type(8))) short short8;
typedef __attribute__((ext_vector_type(4))) float f32x4;

__device__ __forceinline__ u16 f2bf(float f) {
  union { float f; unsigned int u; } x; x.f = f;
  unsigned int u = x.u;
  return (u16)((u + 0x7fffu + ((u >> 16) & 1u)) >> 16);
}
__device__ __forceinline__ unsigned int pk_bf16(float a, float b) {
  float2 t; t.x = a; t.y = b;
  __hip_bfloat162 h = __float22bfloat162_rn(t);
  unsigned int u; memcpy(&u, &h, 4);
  return u;
}
__device__ __forceinline__ void gl_lds16(const u16* g, u16* l) {
  __builtin_amdgcn_global_load_lds((const __attribute__((address_space(1))) void*)g,
                                   (__attribute__((address_space(3))) void*)l, 16, 0, 0);
}

// P-redistribution: (W[t_even], W[t_odd]) -> (B[s][j], B[s][j+2]) in 2 permlane swaps.
__device__ __forceinline__ void pl_swap(unsigned int& a, unsigned int& b) {
  auto r1 = __builtin_amdgcn_permlane32_swap(a, b, false, false);
  auto r2 = __builtin_amdgcn_permlane16_swap(r1[0], r1[1], false, false);
  a = r2[0]; b = r2[1];
}

// scale(1/sqrt(64)) * log2(e), folded into Q at the QKV epilogue
#define SCALE_LOG2E 0.18033688011112042f

// ---------------- x ingestion: fp32 -> internal bf16 ----------------
__global__ void __launch_bounds__(256) conv_x(
    const float* __restrict__ in, u16* __restrict__ out, int n4) {
  const int t = blockIdx.x * 256 + threadIdx.x;
  if (t >= n4) return;
  const float4 v = ((const float4*)in)[t];
  uint2 o;
  o.x = pk_bf16(v.x, v.y);
  o.y = pk_bf16(v.z, v.w);
  ((uint2*)out)[t] = o;
}

// ---- 64x64-tile weight transpose, fp32 in -> bf16 out, all 4 weights via z ----
__global__ void __launch_bounds__(256) transpose_w(
    const float* __restrict__ W0, const float* __restrict__ W1,
    const float* __restrict__ W2, const float* __restrict__ W3,
    u16* __restrict__ Wt) {
  __shared__ alignas(16) u16 t[64][65];
  const int z = blockIdx.z;
  const float* in = (z == 0) ? W0 : (z == 1) ? W1 : (z == 2) ? W2 : W3;
  u16* out = Wt + (size_t)z * 1024 * 1024;
  const int tx = threadIdx.x & 63, ty = threadIdx.x >> 6;
  const int r0 = blockIdx.y * 64, c0 = blockIdx.x * 64;
#pragma unroll
  for (int rr = ty; rr < 64; rr += 4) t[rr][tx] = f2bf(in[(size_t)(r0 + rr) * 1024 + c0 + tx]);
  __syncthreads();
#pragma unroll
  for (int rr = ty; rr < 64; rr += 4) out[(size_t)(c0 + rr) * 1024 + r0 + tx] = t[tx][rr];
}

// ---------------- GEMM core: 128x128 tile, BK=64, single-buffered, T2 swizzle ----
// Best-measured GEMM inner structure (R8/R12). Conflict-free LDS reads (8 slots x
// 8 lanes = 2 lanes/bank). This round tests ONE variable on top of it: XCD-
// clustered grids (R13) so same-A-panel blocks share one XCD's L2. Traffic math:
// default scatter pushes ~800 MB of A/W re-reads per GEMM through L3 (~6.7 TB/s
// = at ceiling); clustering makes A re-reads L2-hits (2 MB slice per XCD).
__device__ __forceinline__ void gemm_core(
    const u16* __restrict__ A, const u16* __restrict__ Bt,
    u16* As, u16* Bs, int m0, int n0, int K, f32x4 (&acc)[4][4]) {
  const int tid = threadIdx.x;
  const int wave = tid >> 6, lane = tid & 63;
  const int quad = lane >> 4, l16 = lane & 15;
  const int wr = wave >> 1, wc = wave & 1;
  const int lr8 = lane >> 3;                       // row within 8-row group
  const int cbg = ((lane & 7) ^ lr8) * 8;          // swizzled source chunk
  const int sw = (l16 & 7);                        // read-side swizzle
  for (int k0 = 0; k0 < K; k0 += 64) {
    __syncthreads();
#pragma unroll
    for (int u = 0; u < 4; ++u) {
      gl_lds16(A  + (size_t)(m0 + u * 32 + wave * 8 + lr8) * K + k0 + cbg,
               &As[u * 2048 + wave * 512]);
      gl_lds16(Bt + (size_t)(n0 + u * 32 + wave * 8 + lr8) * K + k0 + cbg,
               &Bs[u * 2048 + wave * 512]);
    }
    __syncthreads();
#pragma unroll
    for (int ks = 0; ks < 2; ++ks) {
      const int kc = ((ks * 4 + quad) ^ sw) * 8;
      short8 af[4], bfr[4];
#pragma unroll
      for (int i = 0; i < 4; ++i)
        af[i] = *(const short8*)&As[(wr * 64 + i * 16 + l16) * 64 + kc];
#pragma unroll
      for (int j = 0; j < 4; ++j)
        bfr[j] = *(const short8*)&Bs[(wc * 64 + j * 16 + l16) * 64 + kc];
#pragma unroll
      for (int i = 0; i < 4; ++i)
#pragma unroll
        for (int j = 0; j < 4; ++j)
          acc[i][j] = __builtin_amdgcn_mfma_f32_16x16x32_bf16(af[i], bfr[j], acc[i][j], 0, 0, 0);
    }
  }
}

// ---------------- fused QKV GEMM (XCD-clustered 1-D grid, 1536 blocks) ----------
// XCD x owns m-panels m = x (mod 8); within an XCD: n fastest, then m-slot, then
// tsel -> A-slice (8 panels = 2 MB) becomes L2-resident; A re-reads (48 MB/XCD
// before) become L2 hits. Bijective: i = ((tsel*64 + mslot*8 + n) << 3) | xcd.
// Bit-identical math vs R12 (only block->tile assignment changes).
__global__ void __launch_bounds__(256) gemm_qkv(
    const u16* __restrict__ A, const u16* __restrict__ Wt,
    const float* __restrict__ bq, const float* __restrict__ bk, const float* __restrict__ bv,
    u16* __restrict__ Qb, u16* __restrict__ Kb, u16* __restrict__ Vtb) {
  __shared__ alignas(16) u16 As[128 * 64];
  __shared__ alignas(16) u16 Bs[128 * 64];
  const int idx = blockIdx.x;
  const int xcd = idx & 7, j = idx >> 3;           // j in [0,192)
  const int tsel = j >> 6, r = j & 63;
  const int n0 = (r & 7) * 128;
  const int m0 = ((r >> 3) * 8 + xcd) * 128;
  const u16* Bt = Wt + (size_t)tsel * 1048576;
  const float* bias = (tsel == 0) ? bq : (tsel == 1) ? bk : bv;

  f32x4 acc[4][4];
#pragma unroll
  for (int i = 0; i < 4; ++i)
#pragma unroll
    for (int jj = 0; jj < 4; ++jj) acc[i][jj] = (f32x4){0.f, 0.f, 0.f, 0.f};

  gemm_core(A, Bt, As, Bs, m0, n0, 1024, acc);

  const int tid = threadIdx.x;
  const int wave = tid >> 6, lane = tid & 63;
  const int quad = lane >> 4, l16 = lane & 15;
  const int wr = wave >> 1, wc = wave & 1;

  if (tsel < 2) {
    u16* C = tsel ? Kb : Qb;
    const float scl = tsel ? 1.0f : SCALE_LOG2E;  // fold softmax scale*log2e into Q
#pragma unroll
    for (int jj = 0; jj < 4; ++jj) {
      const int n = n0 + wc * 64 + jj * 16 + l16;
      const float bvf = bias[n];
      const int h = n >> 6, d = n & 63;
#pragma unroll
      for (int i = 0; i < 4; ++i) {
        const int mbase = m0 + wr * 64 + i * 16 + quad * 4;
#pragma unroll
        for (int rr = 0; rr < 4; ++rr) {
          const int m = mbase + rr;
          const int b = m >> 11, s = m & 2047;
          C[((((size_t)b * 16 + h) * 2048) + s) * 64 + d] = f2bf((acc[i][jj][rr] + bvf) * scl);
        }
      }
    }
  } else {
#pragma unroll
    for (int jj = 0; jj < 4; ++jj) {
      const int n = n0 + wc * 64 + jj * 16 + l16;
      const float bvf = bias[n];
      const int h = n >> 6, d = n & 63;
#pragma unroll
      for (int i = 0; i < 4; ++i) {
        const int mbase = m0 + wr * 64 + i * 16 + quad * 4;  // s, multiple of 4
        const int b = mbase >> 11, s = mbase & 2047;
        uint2 o;
        o.x = pk_bf16(acc[i][jj][0] + bvf, acc[i][jj][1] + bvf);
        o.y = pk_bf16(acc[i][jj][2] + bvf, acc[i][jj][3] + bvf);
        *(uint2*)&Vtb[(((size_t)b * 16 + h) * 64 + d) * 2048 + s] = o;
      }
    }
  }
}

// ---------------- output-projection GEMM: fp32 out (XCD-clustered, 512 blocks) ---
__global__ void __launch_bounds__(256) gemm_out(
    const u16* __restrict__ A, const u16* __restrict__ Bt,
    const float* __restrict__ bias, float* __restrict__ C, int N) {
  __shared__ alignas(16) u16 As[128 * 64];
  __shared__ alignas(16) u16 Bs[128 * 64];
  const int idx = blockIdx.x;
  const int xcd = idx & 7, j = idx >> 3;           // j in [0,64)
  const int n0 = (j & 7) * 128;
  const int m0 = ((j >> 3) * 8 + xcd) * 128;
  f32x4 acc[4][4];
#pragma unroll
  for (int i = 0; i < 4; ++i)
#pragma unroll
    for (int jj = 0; jj < 4; ++jj) acc[i][jj] = (f32x4){0.f, 0.f, 0.f, 0.f};

  gemm_core(A, Bt, As, Bs, m0, n0, 1024, acc);

  const int tid = threadIdx.x;
  const int wave = tid >> 6, lane = tid & 63;
  const int quad = lane >> 4, l16 = lane & 15;
  const int wr = wave >> 1, wc = wave & 1;
#pragma unroll
  for (int jj = 0; jj < 4; ++jj) {
    const int n = n0 + wc * 64 + jj * 16 + l16;
    const float bvf = bias[n];
#pragma unroll
    for (int i = 0; i < 4; ++i) {
      const int mbase = m0 + wr * 64 + i * 16 + quad * 4;
#pragma unroll
      for (int rr = 0; rr < 4; ++rr)
        C[(size_t)(mbase + rr) * N + n] = acc[i][jj][rr] + bvf;
    }
  }
}

// ---------------- Flash attention: K/V LDS dbuf, Q direct-to-reg (32 KB LDS) ----
// Unchanged from R12-best (~122.5 us; pinned by per-iter serial chain after
// 5 orthogonal null interventions).
__global__ void __launch_bounds__(256) flash_attn(
    const u16* __restrict__ Q, const u16* __restrict__ Kp,
    const u16* __restrict__ Vt, u16* __restrict__ Aout) {
  __shared__ alignas(16) u16 Ks[2][64 * 64];
  __shared__ alignas(16) u16 Vs[2][64 * 64];       // [d][s] tiles

  const int tid = threadIdx.x;
  const int wave = tid >> 6;
  const int lane = tid & 63;
  const int quad = lane >> 4;
  const int l16 = lane & 15;

  // bijective XCD-clustering remap of the 1024-block grid
  const int i = blockIdx.x;
  const int bh = (i & 7) * 8 + (i >> 7);           // XCD (i&7) owns 8 consecutive heads
  const int q0 = ((i >> 3) & 15) * 128;
  const int b = bh >> 4, h = bh & 15;

  const u16* Qg = Q + (size_t)bh * 2048 * 64;
  const u16* Kg = Kp + (size_t)bh * 2048 * 64;
  const u16* Vg = Vt + (size_t)bh * 64 * 2048;

  const int lr8 = lane >> 3;                       // row within 8-row chunk
  const int cbg = ((lane & 7) ^ lr8) * 8;          // swizzled global chunk offset

  // prologue: stage K/V tile 0 into buf 0
#pragma unroll
  for (int t = 0; t < 2; ++t) {
    const int c = wave * 2 + t;
    gl_lds16(Kg + (size_t)(c * 8 + lr8) * 64 + cbg, &Ks[0][c * 8 * 64]);
    gl_lds16(Vg + (size_t)(c * 8 + lr8) * 2048 + cbg, &Vs[0][c * 8 * 64]);
  }

  // Q fragments: direct global->reg, one time (loop-invariant, bit-identical)
  short8 qf[2][2];
#pragma unroll
  for (int qb = 0; qb < 2; ++qb)
#pragma unroll
    for (int ks = 0; ks < 2; ++ks)
      qf[qb][ks] = *(const short8*)&Qg[(size_t)(q0 + wave * 32 + qb * 16 + l16) * 64 + (ks * 4 + quad) * 8];

  f32x4 oacc[2][4];
#pragma unroll
  for (int qb = 0; qb < 2; ++qb)
#pragma unroll
    for (int t = 0; t < 4; ++t) oacc[qb][t] = (f32x4){0.f, 0.f, 0.f, 0.f};
  f32x4 lacc[2];
  lacc[0] = (f32x4){0.f, 0.f, 0.f, 0.f};
  lacc[1] = (f32x4){0.f, 0.f, 0.f, 0.f};
  const int sw = (l16 & 7) * 8;                    // fragment-read swizzle

  short8 ones;
#pragma unroll
  for (int i2 = 0; i2 < 8; ++i2) ones[i2] = (short)0x3F80;  // 1.0 bf16

  // barrier drains tile-0 K/V staging
  __syncthreads();

  for (int kt = 0; kt < 32; ++kt) {
    const int p = kt & 1;
    if (kt + 1 < 32) {
      const int s1 = (kt + 1) * 64;
#pragma unroll
      for (int t = 0; t < 2; ++t) {
        const int c = wave * 2 + t;
        gl_lds16(Kg + (size_t)(s1 + c * 8 + lr8) * 64 + cbg, &Ks[p ^ 1][c * 8 * 64]);
        gl_lds16(Vg + (size_t)(c * 8 + lr8) * 2048 + s1 + cbg, &Vs[p ^ 1][c * 8 * 64]);
      }
    }
    const u16* Kc = &Ks[p][0];
    const u16* Vc = &Vs[p][0];

    // S^T = K-tile @ Q^T  (Q pre-scaled by scale*log2e)
    f32x4 sacc[2][4];
#pragma unroll
    for (int qb = 0; qb < 2; ++qb)
#pragma unroll
      for (int t = 0; t < 4; ++t) sacc[qb][t] = (f32x4){0.f, 0.f, 0.f, 0.f};
#pragma unroll
    for (int ks = 0; ks < 2; ++ks) {
#pragma unroll
      for (int t = 0; t < 4; ++t) {
        const short8 akf = *(const short8*)&Kc[(t * 16 + l16) * 64 + (((ks * 4 + quad) * 8) ^ sw)];
#pragma unroll
        for (int qb = 0; qb < 2; ++qb)
          sacc[qb][t] = __builtin_amdgcn_mfma_f32_16x16x32_bf16(akf, qf[qb][ks], sacc[qb][t], 0, 0, 0);
      }
    }

    // max-free softmax + in-register redistribution to B-fragment layout.
    short8 bpf[2][2];
#pragma unroll
    for (int qb = 0; qb < 2; ++qb) {
      unsigned int w[4][2];
#pragma unroll
      for (int t = 0; t < 4; ++t) {
        const float p0 = __builtin_amdgcn_exp2f(sacc[qb][t][0]);
        const float p1 = __builtin_amdgcn_exp2f(sacc[qb][t][1]);
        const float p2 = __builtin_amdgcn_exp2f(sacc[qb][t][2]);
        const float p3 = __builtin_amdgcn_exp2f(sacc[qb][t][3]);
        w[t][0] = pk_bf16(p0, p1);
        w[t][1] = pk_bf16(p2, p3);
      }
      pl_swap(w[0][0], w[1][0]);
      pl_swap(w[0][1], w[1][1]);
      pl_swap(w[2][0], w[3][0]);
      pl_swap(w[2][1], w[3][1]);
      union { short8 s8; unsigned int u[4]; } pb;
      pb.u[0] = w[0][0]; pb.u[1] = w[0][1]; pb.u[2] = w[1][0]; pb.u[3] = w[1][1];
      bpf[qb][0] = pb.s8;
      pb.u[0] = w[2][0]; pb.u[1] = w[2][1]; pb.u[2] = w[3][0]; pb.u[3] = w[3][1];
      bpf[qb][1] = pb.s8;
    }

    // l += ones @ P^T (row-sum on the matrix pipe)
#pragma unroll
    for (int s = 0; s < 2; ++s)
#pragma unroll
      for (int qb = 0; qb < 2; ++qb)
        lacc[qb] = __builtin_amdgcn_mfma_f32_16x16x32_bf16(ones, bpf[qb][s], lacc[qb], 0, 0, 0);

    // O^T += V-tile @ P^T
#pragma unroll
    for (int s = 0; s < 2; ++s) {
#pragma unroll
      for (int t = 0; t < 4; ++t) {
        const short8 avf = *(const short8*)&Vc[(t * 16 + l16) * 64 + (((s * 4 + quad) * 8) ^ sw)];
#pragma unroll
        for (int qb = 0; qb < 2; ++qb)
          oacc[qb][t] = __builtin_amdgcn_mfma_f32_16x16x32_bf16(avf, bpf[qb][s], oacc[qb][t], 0, 0, 0);
      }
    }

    // single barrier per iter: drains next-tile staging (vmcnt) and orders
    // this iter's LDS reads before the next overwrite of buf^1
    __syncthreads();
  }

#pragma unroll
  for (int qb = 0; qb < 2; ++qb) {
    const float inv = 1.0f / lacc[qb][0];
    const int qrow = q0 + wave * 32 + qb * 16 + l16;
    const size_t base = ((size_t)b * 2048 + qrow) * 1024 + h * 64 + quad * 4;
#pragma unroll
    for (int t = 0; t < 4; ++t) {
      uint2 o;
      o.x = pk_bf16(oacc[qb][t][0] * inv, oacc[qb][t][1] * inv);
      o.y = pk_bf16(oacc[qb][t][2] * inv, oacc[qb][t][3] * inv);
      *(uint2*)&Aout[base + t * 16] = o;
    }
  }
}

extern "C" void kernel_launch(void* const* d_in, const int* in_sizes, int n_in,
                              void* d_out, int out_size, void* d_ws, size_t ws_size,
                              hipStream_t stream) {
  (void)in_sizes; (void)n_in; (void)out_size; (void)ws_size;
  const float* x  = (const float*)d_in[0];
  const float* Wq = (const float*)d_in[1];
  const float* bq = (const float*)d_in[2];
  const float* Wk = (const float*)d_in[3];
  const float* bk = (const float*)d_in[4];
  const float* Wv = (const float*)d_in[5];
  const float* bv = (const float*)d_in[6];
  const float* Wo = (const float*)d_in[7];
  const float* bo = (const float*)d_in[8];
  float* out = (float*)d_out;

  u16* ws = (u16*)d_ws;
  const size_t SZ = (size_t)4 * 16 * 2048 * 64;  // 16 MiB regions
  u16* xb   = ws;               // A (reused for Attn after gemm_qkv)
  u16* Qb   = ws + SZ;          // B
  u16* Kb   = ws + 2 * SZ;      // C
  u16* Vtb  = ws + 3 * SZ;      // D (V written directly transposed)
  u16* Wt   = ws + 4 * SZ;      // E (4 transposed weights)
  u16* Attn = ws;               // A alias

  conv_x<<<dim3(8192), dim3(256), 0, stream>>>(x, xb, 2097152);
  transpose_w<<<dim3(16, 16, 4), dim3(256), 0, stream>>>(Wq, Wk, Wv, Wo, Wt);
  gemm_qkv<<<dim3(1536), dim3(256), 0, stream>>>(xb, Wt, bq, bk, bv, Qb, Kb, Vtb);
  flash_attn<<<dim3(1024), dim3(256), 0, stream>>>(Qb, Kb, Vtb, Attn);
  gemm_out<<<dim3(512), dim3(256), 0, stream>>>(Attn, Wt + (size_t)3 * 1048576, bo, out, 1024);
}